// Round 6
// baseline (86.819 us; speedup 1.0000x reference)
//
#include <hip/hip_runtime.h>

#define NPTS 8192
#define NQ   2048
#define NBATCH 8
#define KNN  32
#define R2   0.04f   // fp32 cast of python 0.2**2

// Pack pos (AoS, 12B stride) into float4(x,y,z,|p|^2). Norm with explicit
// round-to-nearest ops, no FMA contraction, reference order: (x*x+y*y)+z*z.
__global__ __launch_bounds__(256)
void gg_prep(const float* __restrict__ pos, float4* __restrict__ pack, int total) {
    int i = blockIdx.x * blockDim.x + threadIdx.x;
    if (i >= total) return;
    float x = pos[i * 3 + 0];
    float y = pos[i * 3 + 1];
    float z = pos[i * 3 + 2];
    float n = __fadd_rn(__fadd_rn(__fmul_rn(x, x), __fmul_rn(y, y)), __fmul_rn(z, z));
    pack[i] = make_float4(x, y, z, n);
}

// Branch-free 64-point test: distance (reference op order), ballot, mbcnt
// prefix, exec-masked store, branchless first-hit select. No per-sub-chunk
// control flow; the only branches are per-256-pt-iteration guards.
#define TEST(CQ, COL, FIRST, OP, PV, SUBI)                                         \
    {                                                                              \
        float dot = __fadd_rn(__fadd_rn(__fmul_rn((CQ).x, (PV).x),                 \
                                        __fmul_rn((CQ).y, (PV).y)),                \
                              __fmul_rn((CQ).z, (PV).z));                          \
        float s   = __fsub_rn(__fadd_rn((CQ).w, (PV).w), __fmul_rn(2.0f, dot));    \
        bool keep = !(s > R2);                                                     \
        unsigned long long m = __ballot(keep);                                     \
        int prefix = (int)__builtin_amdgcn_mbcnt_hi(                               \
            (unsigned)(m >> 32), __builtin_amdgcn_mbcnt_lo((unsigned)m, 0u));      \
        int slot = (COL) + prefix;                                                 \
        if (keep && slot < KNN) (OP)[slot] = (SUBI) + lane;                        \
        (FIRST) = ((COL) == 0 && m) ? (SUBI) + (int)__builtin_ctzll(m) : (FIRST);  \
        (COL) += (int)__popcll(m);                                                 \
    }

// One wave per FOUR queries (same batch). 256 points/iteration, loads issued
// one full iteration ahead. Per-query activity guard + early exit checked
// once per iteration (wave-uniform).
__global__ __launch_bounds__(64)
void gg_ballquery(const float4* __restrict__ pack,
                  const int* __restrict__ centroids,
                  int* __restrict__ out) {
    const int lane = threadIdx.x;          // block = 1 wave
    const int w    = blockIdx.x;           // 0 .. 4095
    const int q0   = w * 4;
    const int b    = q0 >> 11;             // 512 waves per batch

    const float4* __restrict__ pp = pack + b * NPTS;

    const float4 cA = pp[centroids[q0 + 0]];
    const float4 cB = pp[centroids[q0 + 1]];
    const float4 cC = pp[centroids[q0 + 2]];
    const float4 cD = pp[centroids[q0 + 3]];

    int* __restrict__ oA = out + q0 * KNN;
    int* __restrict__ oB = oA + KNN;
    int* __restrict__ oC = oB + KNN;
    int* __restrict__ oD = oC + KNN;

    int colA = 0, colB = 0, colC = 0, colD = 0;
    int fA = NPTS, fB = NPTS, fC = NPTS, fD = NPTS;

    // Prefetch iteration 0 (points [0, 256))
    float4 r0 = pp[lane];
    float4 r1 = pp[lane + 64];
    float4 r2 = pp[lane + 128];
    float4 r3 = pp[lane + 192];

    #pragma unroll 1
    for (int base = 0; base < NPTS; base += 256) {
        float4 p0 = r0, p1 = r1, p2 = r2, p3 = r3;
        if (base + 256 < NPTS) {            // prefetch next 256 points
            r0 = pp[base + 256 + lane];
            r1 = pp[base + 320 + lane];
            r2 = pp[base + 384 + lane];
            r3 = pp[base + 448 + lane];
        }

        if (colA < KNN) {
            TEST(cA, colA, fA, oA, p0, base);
            TEST(cA, colA, fA, oA, p1, base + 64);
            TEST(cA, colA, fA, oA, p2, base + 128);
            TEST(cA, colA, fA, oA, p3, base + 192);
        }
        if (colB < KNN) {
            TEST(cB, colB, fB, oB, p0, base);
            TEST(cB, colB, fB, oB, p1, base + 64);
            TEST(cB, colB, fB, oB, p2, base + 128);
            TEST(cB, colB, fB, oB, p3, base + 192);
        }
        if (colC < KNN) {
            TEST(cC, colC, fC, oC, p0, base);
            TEST(cC, colC, fC, oC, p1, base + 64);
            TEST(cC, colC, fC, oC, p2, base + 128);
            TEST(cC, colC, fC, oC, p3, base + 192);
        }
        if (colD < KNN) {
            TEST(cD, colD, fD, oD, p0, base);
            TEST(cD, colD, fD, oD, p1, base + 64);
            TEST(cD, colD, fD, oD, p2, base + 128);
            TEST(cD, colD, fD, oD, p3, base + 192);
        }

        if (colA >= KNN && colB >= KNN && colC >= KNN && colD >= KNN) break;
    }

    // Pad tail slots [col, 32) with the first neighbor index.
    if (colA < KNN && colA + lane < KNN) oA[colA + lane] = fA;
    if (colB < KNN && colB + lane < KNN) oB[colB + lane] = fB;
    if (colC < KNN && colC + lane < KNN) oC[colC + lane] = fC;
    if (colD < KNN && colD + lane < KNN) oD[colD + lane] = fD;
}

extern "C" void kernel_launch(void* const* d_in, const int* in_sizes, int n_in,
                              void* d_out, int out_size, void* d_ws, size_t ws_size,
                              hipStream_t stream) {
    const float* pos       = (const float*)d_in[0];   // (8, 8192, 3) f32
    const int*   centroids = (const int*)d_in[1];     // (8, 2048) int32 on device
    int*         out       = (int*)d_out;             // (8, 2048, 32) int32

    float4* pack = (float4*)d_ws;                     // 8*8192*16B = 1 MiB scratch

    const int total = NBATCH * NPTS;                  // 65536 points
    gg_prep<<<dim3((total + 255) / 256), dim3(256), 0, stream>>>(pos, pack, total);

    const int nw = (NBATCH * NQ) / 4;                 // 4096 waves, 1 per block
    gg_ballquery<<<dim3(nw), dim3(64), 0, stream>>>(pack, centroids, out);
}